// Round 13
// baseline (302.402 us; speedup 1.0000x reference)
//
#include <hip/hip_runtime.h>

// Flow_49160195670664: Dopri5 fixed-step integration of dx/dt = A x + B u(t).
// Linear system => x_{n+1} = R x_n + v_n; 4-level scan 8x8x8x64.
// v10: drive GEMM on MFMA (314->288).
// v11: chain kernels 512 thr = 8 waves x TWO 16-col N-tiles (was 16 waves x 1).
// Rationale (r3/r12 model): per-step time == LDS A-frag read throughput.
// 16 waves re-reading full x = 256KB LDS/step/CU = ~1.75us/step; 2 tiles/wave
// reads A-frags ONCE for both tiles -> 128KB/step/CU -> ~1.0-1.2us/step over
// ~66 sequential steps. r2's attempt at this shape spilled because
// __launch_bounds__(512,2) capped VGPR at 128 < 128 frag regs; (512,1) caps
// at 256 (8-wave block = 2 waves/SIMD) and ~206 fits.

#define TPTS 32768

typedef __attribute__((ext_vector_type(8))) short short8;
typedef __attribute__((ext_vector_type(4))) float float4v;
typedef unsigned short ushort_t;

__device__ __forceinline__ ushort_t bf16_hi(float f) {
  unsigned u = __builtin_bit_cast(unsigned, f);
  unsigned r = (u + 0x7FFFu + ((u >> 16) & 1u)) >> 16;
  return (ushort_t)r;
}
__device__ __forceinline__ float bf16_f(ushort_t h) {
  unsigned u = ((unsigned)h) << 16;
  return __builtin_bit_cast(float, u);
}

// ---------------------------------------------------------------------------
// MFMA chain body. 512 thr = 8 waves; wave w owns output cols [32w,32w+32) as
// TWO N-tiles of mfma_f32_16x16x32_bf16; 16 chains = M-dim. bf16 hi/lo split
// (x*R ~ xh*Rh + xl*Rh + xh*Rl, fp32 acc), 6 independent accumulators.
// A-frags (x) read once per kt, used for both tiles. V-drive register-
// prefetched one step ahead. blk is LOGICAL.
// MODE 0: power  (CLEN steps, x0 = I cols; Out = M^CLEN row-major fp32 + h/l)
// MODE 1: reduce (x0 = V row0 of chain, drive rows 1..CLEN-1; Out[chain]=final)
// MODE 2: expand (x0 = X0[chain], drive rows 0..CLEN-2; Out rows chain*CLEN+j)
// Arena: xh @0 (16KB), xl @16K (16KB), hist @32K (16KB MODE0/1, 80KB MODE2).
template <int MODE, int CLEN>
__device__ __forceinline__ void chain_body(char* arena, const ushort_t* Mh, const ushort_t* Ml,
                                           const float* X0, const float* V,
                                           float* Out, ushort_t* OutH, ushort_t* OutL, int blk) {
  constexpr int STEPS = (MODE == 0) ? CLEN : CLEN - 1;
  int t = threadIdx.x;
  int w = t >> 6, l = t & 63;   // w 0..7
  int q = l >> 4, c16 = l & 15;
  int n0 = w * 32;
  ushort_t (*xh)[32][16][8] = reinterpret_cast<ushort_t(*)[32][16][8]>(arena);
  ushort_t (*xl)[32][16][8] = reinterpret_cast<ushort_t(*)[32][16][8]>(arena + 16384);
  float (*hist)[16][256] = reinterpret_cast<float(*)[16][256]>(arena + 32768);
  // B-frags: B[k][n] = M[n][k]; lane holds B[kt*32+q*8+j][n0+nt*16+c16]
  short8 bh[2][8], bl[2][8];
#pragma unroll
  for (int nt = 0; nt < 2; nt++)
#pragma unroll
    for (int kt = 0; kt < 8; kt++) {
      size_t offs = (size_t)(n0 + nt * 16 + c16) * 256 + kt * 32 + q * 8;
      bh[nt][kt] = *(const short8*)(Mh + offs);
      bl[nt][kt] = *(const short8*)(Ml + offs);
    }
  // initial x (and row-0 store for MODE 2): 1024 float4 over 512 thr
  for (int e = t; e < 1024; e += 512) {
    int c = e >> 6, qq = (e & 63) * 4;
    int cg = blk * 16 + c;
    float4 v4;
    if (MODE == 0) {
      v4 = make_float4(qq == cg ? 1.f : 0.f, qq + 1 == cg ? 1.f : 0.f,
                       qq + 2 == cg ? 1.f : 0.f, qq + 3 == cg ? 1.f : 0.f);
    } else if (MODE == 1) {
      v4 = *(const float4*)(V + (size_t)cg * CLEN * 256 + qq);
    } else {
      v4 = *(const float4*)(X0 + (size_t)cg * 256 + qq);
      *(float4*)(Out + ((size_t)cg * CLEN) * 256 + qq) = v4;
    }
    float vals[4] = {v4.x, v4.y, v4.z, v4.w};
#pragma unroll
    for (int i = 0; i < 4; i++) {
      int n = qq + i;
      ushort_t h = bf16_hi(vals[i]);
      xh[0][n >> 3][c][n & 7] = h;
      xl[0][n >> 3][c][n & 7] = bf16_hi(vals[i] - bf16_f(h));
    }
  }
  // per-lane drive prefetch for step 1 (chain q*4+r, col n0+nt*16+c16)
  float vnext[8];
  if (MODE != 0) {
#pragma unroll
    for (int r = 0; r < 4; r++)
#pragma unroll
      for (int nt = 0; nt < 2; nt++) {
        int cg = blk * 16 + q * 4 + r;
        int drow = (MODE == 1) ? 1 : 0;
        vnext[r * 2 + nt] = V[((size_t)cg * CLEN + drow) * 256 + n0 + nt * 16 + c16];
      }
  }
  __syncthreads();
  for (int s = 1; s <= STEPS; s++) {
    int cur = (s - 1) & 1, nxt = s & 1;
    // MODE 2: flush rows s-4..s-1 (slots row%5) — mod-5 disjoint vs writes
    if (MODE == 2 && s >= 5 && ((s - 1) & 3) == 0) {
      int rbase = s - 4;
      for (int e = t; e < 4096; e += 512) {
        int slot = e >> 10;
        int rem = e & 1023;
        int c = rem >> 6, qq = (rem & 63) * 4;
        int row = rbase + slot;
        int cg = blk * 16 + c;
        *(float4*)(Out + ((size_t)cg * CLEN + row) * 256 + qq) = *(const float4*)&hist[row % 5][c][qq];
      }
    }
    // drive: consume prefetched, issue next step's loads (hidden under MFMAs)
    float vc[8];
    if (MODE != 0) {
#pragma unroll
      for (int i2 = 0; i2 < 8; i2++) vc[i2] = vnext[i2];
      if (s < STEPS) {
        int drow = (MODE == 1) ? (s + 1) : s;
#pragma unroll
        for (int r = 0; r < 4; r++)
#pragma unroll
          for (int nt = 0; nt < 2; nt++)
            vnext[r * 2 + nt] =
                V[((size_t)(blk * 16 + q * 4 + r) * CLEN + drow) * 256 + n0 + nt * 16 + c16];
      }
    }
    // pin frags: rw asm operand => value must live in VGPRs, reload illegal
#pragma unroll
    for (int nt = 0; nt < 2; nt++)
#pragma unroll
      for (int kt = 0; kt < 8; kt++) {
        asm volatile("" : "+v"(bh[nt][kt]));
        asm volatile("" : "+v"(bl[nt][kt]));
      }
    float4v a0h = {0.f, 0.f, 0.f, 0.f}, a1h = {0.f, 0.f, 0.f, 0.f};
    float4v a0l = {0.f, 0.f, 0.f, 0.f}, a1l = {0.f, 0.f, 0.f, 0.f};
    float4v a0c = {0.f, 0.f, 0.f, 0.f}, a1c = {0.f, 0.f, 0.f, 0.f};
#pragma unroll
    for (int kt = 0; kt < 8; kt++) {
      short8 ah = *(const short8*)&xh[cur][kt * 4 + q][c16][0];
      short8 al = *(const short8*)&xl[cur][kt * 4 + q][c16][0];
      a0h = __builtin_amdgcn_mfma_f32_16x16x32_bf16(ah, bh[0][kt], a0h, 0, 0, 0);
      a1h = __builtin_amdgcn_mfma_f32_16x16x32_bf16(ah, bh[1][kt], a1h, 0, 0, 0);
      a0l = __builtin_amdgcn_mfma_f32_16x16x32_bf16(al, bh[0][kt], a0l, 0, 0, 0);
      a1l = __builtin_amdgcn_mfma_f32_16x16x32_bf16(al, bh[1][kt], a1l, 0, 0, 0);
      a0c = __builtin_amdgcn_mfma_f32_16x16x32_bf16(ah, bl[0][kt], a0c, 0, 0, 0);
      a1c = __builtin_amdgcn_mfma_f32_16x16x32_bf16(ah, bl[1][kt], a1c, 0, 0, 0);
    }
    // epilogue: C/D layout chain=(q*4+r), col=c16 (m89-verified)
#pragma unroll
    for (int nt = 0; nt < 2; nt++) {
#pragma unroll
      for (int r = 0; r < 4; r++) {
        int c = q * 4 + r;
        int n = n0 + nt * 16 + c16;
        float val = (nt == 0) ? (a0h[r] + a0l[r] + a0c[r]) : (a1h[r] + a1l[r] + a1c[r]);
        if (MODE != 0) val += vc[r * 2 + nt];
        int cg = blk * 16 + c;
        if (MODE == 2) hist[s % 5][c][n] = val;
        if (MODE == 1 && s == STEPS) Out[(size_t)cg * 256 + n] = val;
        if (MODE == 0 && s == STEPS) {
          ushort_t h2 = bf16_hi(val);
          Out[(size_t)n * 256 + cg] = val;
          OutH[(size_t)n * 256 + cg] = h2;
          OutL[(size_t)n * 256 + cg] = bf16_hi(val - bf16_f(h2));
        }
        ushort_t h = bf16_hi(val);
        xh[nxt][n >> 3][c][n & 7] = h;
        xl[nxt][n >> 3][c][n & 7] = bf16_hi(val - bf16_f(h));
      }
    }
    __syncthreads();
  }
  if (MODE == 2) {   // final rows STEPS-2..STEPS
    for (int e = t; e < 3072; e += 512) {
      int slot = e >> 10;
      int rem = e & 1023;
      int c = rem >> 6, qq = (rem & 63) * 4;
      int row = (STEPS - 2) + slot;
      int cg = blk * 16 + c;
      *(float4*)(Out + ((size_t)cg * CLEN + row) * 256 + qq) = *(const float4*)&hist[row % 5][c][qq];
    }
  }
}

// ---------------------------------------------------------------------------
// Hermite tap value: row n, k = t*32+c -> {u_n, m_n, u_{n+1}, m_{n+1}}[t][c].
// Row TPTS-1 = 0 (pad).
__device__ __forceinline__ float tap_val(const float* __restrict__ u, int n, int k) {
  if (n >= TPTS - 1) return 0.f;
  int t = k >> 5, c = k & 31;
  if (t == 0) return u[(size_t)n * 32 + c];
  if (t == 2) return u[(size_t)(n + 1) * 32 + c];
  int kk = (t == 1) ? n : n + 1;
  if (kk == 0) return u[32 + c] - u[c];
  if (kk == TPTS - 1) return u[(size_t)(TPTS - 1) * 32 + c] - u[(size_t)(TPTS - 2) * 32 + c];
  return 0.5f * (u[(size_t)(kk + 1) * 32 + c] - u[(size_t)(kk - 1) * 32 + c]);
}

// Drive GEMM on MFMA, 512 threads: V0[rows g*64..g*64+64)[256] =
// taps[64][128] @ F[128][256]; wave w owns 2 N-tiles at cols [32w,32w+32).
// 4 groups of 16 rows; per group: stage taps bf16 hi/lo to LDS in A-frag
// layout [k>>3][row][k&7] (4 taps/thread), 24 MFMA per wave.
// Arena: ah @0 (4KB), al @4K (4KB).
__device__ __forceinline__ void drive_body(char* arena, const float* __restrict__ u,
                                           const ushort_t* __restrict__ Fh,
                                           const ushort_t* __restrict__ Fl,
                                           float* __restrict__ V0, int g) {
  int t = threadIdx.x;
  int w = t >> 6, l = t & 63;
  int q = l >> 4, c16 = l & 15;
  int n0 = w * 32;
  ushort_t (*ah)[16][8] = reinterpret_cast<ushort_t(*)[16][8]>(arena);         // [16][16][8]
  ushort_t (*al)[16][8] = reinterpret_cast<ushort_t(*)[16][8]>(arena + 4096);
  // B-frags: B[k][n] = F[k][n] = Fh/Fl[n*128 + k]
  short8 bh[2][4], bl[2][4];
#pragma unroll
  for (int nt = 0; nt < 2; nt++)
#pragma unroll
    for (int kt = 0; kt < 4; kt++) {
      size_t offs = (size_t)(n0 + nt * 16 + c16) * 128 + kt * 32 + q * 8;
      bh[nt][kt] = *(const short8*)(Fh + offs);
      bl[nt][kt] = *(const short8*)(Fl + offs);
    }
  int rowbase = g * 64;
  int srow = t >> 5;        // staging row 0..15
  int kq = (t & 31) * 4;    // staging k 0,4,...,124 (4 taps, same 8-group)
  for (int grp = 0; grp < 4; grp++) {
    int rb = rowbase + grp * 16;
    float v0 = tap_val(u, rb + srow, kq);
    float v1 = tap_val(u, rb + srow, kq + 1);
    float v2 = tap_val(u, rb + srow, kq + 2);
    float v3 = tap_val(u, rb + srow, kq + 3);
    ushort_t h0 = bf16_hi(v0), h1 = bf16_hi(v1), h2 = bf16_hi(v2), h3 = bf16_hi(v3);
    ushort_t lo0 = bf16_hi(v0 - bf16_f(h0)), lo1 = bf16_hi(v1 - bf16_f(h1));
    ushort_t lo2 = bf16_hi(v2 - bf16_f(h2)), lo3 = bf16_hi(v3 - bf16_f(h3));
    *(unsigned*)&ah[kq >> 3][srow][kq & 7] = (unsigned)h0 | ((unsigned)h1 << 16);
    *(unsigned*)&ah[kq >> 3][srow][(kq & 7) + 2] = (unsigned)h2 | ((unsigned)h3 << 16);
    *(unsigned*)&al[kq >> 3][srow][kq & 7] = (unsigned)lo0 | ((unsigned)lo1 << 16);
    *(unsigned*)&al[kq >> 3][srow][(kq & 7) + 2] = (unsigned)lo2 | ((unsigned)lo3 << 16);
    __syncthreads();
    float4v a0h = {0.f, 0.f, 0.f, 0.f}, a1h = {0.f, 0.f, 0.f, 0.f};
    float4v a0l = {0.f, 0.f, 0.f, 0.f}, a1l = {0.f, 0.f, 0.f, 0.f};
    float4v a0c = {0.f, 0.f, 0.f, 0.f}, a1c = {0.f, 0.f, 0.f, 0.f};
#pragma unroll
    for (int kt = 0; kt < 4; kt++) {
      short8 a_h = *(const short8*)&ah[kt * 4 + q][c16][0];
      short8 a_l = *(const short8*)&al[kt * 4 + q][c16][0];
      a0h = __builtin_amdgcn_mfma_f32_16x16x32_bf16(a_h, bh[0][kt], a0h, 0, 0, 0);
      a1h = __builtin_amdgcn_mfma_f32_16x16x32_bf16(a_h, bh[1][kt], a1h, 0, 0, 0);
      a0l = __builtin_amdgcn_mfma_f32_16x16x32_bf16(a_l, bh[0][kt], a0l, 0, 0, 0);
      a1l = __builtin_amdgcn_mfma_f32_16x16x32_bf16(a_l, bh[1][kt], a1l, 0, 0, 0);
      a0c = __builtin_amdgcn_mfma_f32_16x16x32_bf16(a_h, bl[0][kt], a0c, 0, 0, 0);
      a1c = __builtin_amdgcn_mfma_f32_16x16x32_bf16(a_h, bl[1][kt], a1c, 0, 0, 0);
    }
    // C/D: row = q*4+r, col = c16 within each tile
#pragma unroll
    for (int nt = 0; nt < 2; nt++)
#pragma unroll
      for (int r = 0; r < 4; r++) {
        int row = rb + q * 4 + r;
        float val = (nt == 0) ? (a0h[r] + a0l[r] + a0c[r]) : (a1h[r] + a1l[r] + a1c[r]);
        V0[(size_t)row * 256 + n0 + nt * 16 + c16] = val;
      }
    __syncthreads();
  }
}

// ---------------------------------------------------------------------------
// Fused kernels (disjoint block ranges; no cross-block dependencies in-kernel)
__global__ __launch_bounds__(512, 1) void pow8_gemm(const ushort_t* Rh, const ushort_t* Rl,
                                                    float* PowFp, ushort_t* R8h, ushort_t* R8l,
                                                    const float* u, const ushort_t* Fh,
                                                    const ushort_t* Fl, float* V0) {
  __shared__ __attribute__((aligned(16))) char arena[49152];
  int blk = blockIdx.x;
  if (blk < 16)
    chain_body<0, 8>(arena, Rh, Rl, nullptr, nullptr, PowFp, R8h, R8l, blk);
  else
    drive_body(arena, u, Fh, Fl, V0, blk - 16);
}

__global__ __launch_bounds__(512, 1) void pow64_reduce0(const ushort_t* R8h, const ushort_t* R8l,
                                                        float* PowFp, ushort_t* R64h, ushort_t* R64l,
                                                        const ushort_t* Rh, const ushort_t* Rl,
                                                        const float* V0, float* V1) {
  __shared__ __attribute__((aligned(16))) char arena[49152];
  int blk = blockIdx.x;
  if (blk < 16)
    chain_body<0, 8>(arena, R8h, R8l, nullptr, nullptr, PowFp, R64h, R64l, blk);
  else
    chain_body<1, 8>(arena, Rh, Rl, nullptr, V0, V1, nullptr, nullptr, blk - 16);
}

__global__ __launch_bounds__(512, 1) void pow512_reduce1(const ushort_t* R64h, const ushort_t* R64l,
                                                         float* R512fp, ushort_t* R512h, ushort_t* R512l,
                                                         const ushort_t* R8h, const ushort_t* R8l,
                                                         const float* V1, float* V2) {
  __shared__ __attribute__((aligned(16))) char arena[49152];
  int blk = blockIdx.x;
  if (blk < 16)
    chain_body<0, 8>(arena, R64h, R64l, nullptr, nullptr, R512fp, R512h, R512l, blk);
  else
    chain_body<1, 8>(arena, R8h, R8l, nullptr, V1, V2, nullptr, nullptr, blk - 16);
}

__global__ __launch_bounds__(512, 1) void reduce2_k(const ushort_t* R64h, const ushort_t* R64l,
                                                    const float* V2, float* V3) {
  __shared__ __attribute__((aligned(16))) char arena[49152];
  chain_body<1, 8>(arena, R64h, R64l, nullptr, V2, V3, nullptr, nullptr, blockIdx.x);
}

__global__ __launch_bounds__(512, 1) void expand2_k(const ushort_t* R64h, const ushort_t* R64l,
                                                    const float* X3, const float* V2, float* X2) {
  __shared__ __attribute__((aligned(16))) char arena[114688];
  chain_body<2, 8>(arena, R64h, R64l, X3, V2, X2, nullptr, nullptr, blockIdx.x);
}

__global__ __launch_bounds__(512, 1) void expand1_k(const ushort_t* R8h, const ushort_t* R8l,
                                                    const float* X2, const float* V1, float* X1) {
  __shared__ __attribute__((aligned(16))) char arena[114688];
  chain_body<2, 8>(arena, R8h, R8l, X2, V1, X1, nullptr, nullptr, blockIdx.x);
}

__global__ __launch_bounds__(512, 1) void expand0_k(const ushort_t* Rh, const ushort_t* Rl,
                                                    const float* X1, const float* V0, float* xout) {
  __shared__ __attribute__((aligned(16))) char arena[114688];
  chain_body<2, 8>(arena, Rh, Rl, X1, V0, xout, nullptr, nullptr, blockIdx.x);
}

// ---------------------------------------------------------------------------
// y = x @ C^T + u @ D^T. Register-tiled 4x4 (v5-verified).
__global__ __launch_bounds__(256) void y_kernel(const float* __restrict__ x, const float* __restrict__ u,
                                                const float* __restrict__ Cm, const float* __restrict__ Dm,
                                                float* __restrict__ y) {
  __shared__ float CsT[256][36];
  __shared__ float DsT[32][36];
  int tid = threadIdx.x;
  for (int k = tid; k < 8192; k += 256) CsT[k & 255][k >> 8] = Cm[k];
  for (int k = tid; k < 1024; k += 256) DsT[k & 31][k >> 5] = Dm[k];
  __syncthreads();
  int rt = tid >> 3, ct = tid & 7;
  int n0 = blockIdx.x * 128 + rt * 4;
  int o0 = ct * 4;
  float acc[4][4] = {{0.f}};
#pragma unroll 4
  for (int i = 0; i < 256; i += 4) {
    float4 cv0 = *(const float4*)&CsT[i + 0][o0];
    float4 cv1 = *(const float4*)&CsT[i + 1][o0];
    float4 cv2 = *(const float4*)&CsT[i + 2][o0];
    float4 cv3 = *(const float4*)&CsT[i + 3][o0];
#pragma unroll
    for (int r = 0; r < 4; r++) {
      float4 xv = *(const float4*)(x + (size_t)(n0 + r) * 256 + i);
      acc[r][0] += xv.x * cv0.x + xv.y * cv1.x + xv.z * cv2.x + xv.w * cv3.x;
      acc[r][1] += xv.x * cv0.y + xv.y * cv1.y + xv.z * cv2.y + xv.w * cv3.y;
      acc[r][2] += xv.x * cv0.z + xv.y * cv1.z + xv.z * cv2.z + xv.w * cv3.z;
      acc[r][3] += xv.x * cv0.w + xv.y * cv1.w + xv.z * cv2.w + xv.w * cv3.w;
    }
  }
#pragma unroll
  for (int i = 0; i < 32; i += 4) {
    float4 dv0 = *(const float4*)&DsT[i + 0][o0];
    float4 dv1 = *(const float4*)&DsT[i + 1][o0];
    float4 dv2 = *(const float4*)&DsT[i + 2][o0];
    float4 dv3 = *(const float4*)&DsT[i + 3][o0];
#pragma unroll
    for (int r = 0; r < 4; r++) {
      float4 uv = *(const float4*)(u + (size_t)(n0 + r) * 32 + i);
      acc[r][0] += uv.x * dv0.x + uv.y * dv1.x + uv.z * dv2.x + uv.w * dv3.x;
      acc[r][1] += uv.x * dv0.y + uv.y * dv1.y + uv.z * dv2.y + uv.w * dv3.y;
      acc[r][2] += uv.x * dv0.z + uv.y * dv1.z + uv.z * dv2.z + uv.w * dv3.z;
      acc[r][3] += uv.x * dv0.w + uv.y * dv1.w + uv.z * dv2.w + uv.w * dv3.w;
    }
  }
#pragma unroll
  for (int r = 0; r < 4; r++)
    *(float4*)(y + (size_t)(n0 + r) * 32 + o0) =
        make_float4(acc[r][0], acc[r][1], acc[r][2], acc[r][3]);
}

// ---------------------------------------------------------------------------
// AT = A^T (256x256)
__global__ __launch_bounds__(256) void transpose_at(const float* __restrict__ A, float* __restrict__ AT) {
  __shared__ float tile[64][65];
  int bx = blockIdx.x & 3, by = blockIdx.x >> 2;
  int r0 = by * 64, c0 = bx * 64;
  int t = threadIdx.x;
  int lr = t >> 4, lc = (t & 15) * 4;
  for (int rr = lr; rr < 64; rr += 16) {
    float4 v = *(const float4*)(A + (size_t)(r0 + rr) * 256 + c0 + lc);
    tile[rr][lc + 0] = v.x; tile[rr][lc + 1] = v.y; tile[rr][lc + 2] = v.z; tile[rr][lc + 3] = v.w;
  }
  __syncthreads();
  for (int rr = lr; rr < 64; rr += 16) {
    float4 v = make_float4(tile[lc + 0][rr], tile[lc + 1][rr], tile[lc + 2][rr], tile[lc + 3][rr]);
    *(float4*)(AT + (size_t)(c0 + rr) * 256 + r0 + lc) = v;
  }
}

// Unit responses through one Dopri5 step: cols 0..255 -> R fp32 + bf16 hi/lo
// split; cols 256..383 -> Hermite-folded tap matrices, bf16 hi/lo split,
// stored TRANSPOSED as Fh/Fl[n][k] (B-frag-ready for drive_body).
__global__ __launch_bounds__(1024) void unit_resp(const float* __restrict__ AT,
                                                  const float* __restrict__ Bm,
                                                  float* __restrict__ Rout,
                                                  ushort_t* __restrict__ Rh,
                                                  ushort_t* __restrict__ Rl,
                                                  ushort_t* __restrict__ Fh,
                                                  ushort_t* __restrict__ Fl) {
  int blk = blockIdx.x;
  int tid = threadIdx.x;
  int jg = tid >> 8;   // j-group 0..3, also the owned column index cc
  int i = tid & 255;   // output row
  int cc = jg;
  int col = blk * 4 + cc;

  __shared__ float xs4[256][4];
  __shared__ float4 part[4][256];

  const float AA[6][5] = {
      {0.f, 0.f, 0.f, 0.f, 0.f},
      {0.2f, 0.f, 0.f, 0.f, 0.f},
      {3.f / 40.f, 9.f / 40.f, 0.f, 0.f, 0.f},
      {44.f / 45.f, -56.f / 15.f, 32.f / 9.f, 0.f, 0.f},
      {19372.f / 6561.f, -25360.f / 2187.f, 64448.f / 6561.f, -212.f / 729.f, 0.f},
      {9017.f / 3168.f, -355.f / 33.f, 46732.f / 5247.f, 49.f / 176.f, -5103.f / 18656.f}};
  const float BB[6] = {35.f / 384.f, 0.f, 500.f / 1113.f, 125.f / 192.f, -2187.f / 6784.f, 11.f / 84.f};
  const float sv[6] = {0.f, 0.2f, 0.3f, 0.8f, 8.f / 9.f, 1.f};
  float Hm[6][4];
#pragma unroll
  for (int s = 0; s < 6; s++) {
    float ss = sv[s], s2 = ss * ss, s3 = s2 * ss;
    Hm[s][0] = 2.f * s3 - 3.f * s2 + 1.f;
    Hm[s][1] = s3 - 2.f * s2 + ss;
    Hm[s][2] = -2.f * s3 + 3.f * s2;
    Hm[s][3] = s3 - s2;
  }

  // owned-column metadata
  int isF, tt;
  float brow, xc;
  if (col < 256) {
    isF = 0; tt = 0; brow = 0.f;
    xc = (i == col) ? 1.f : 0.f;
  } else {
    isF = 1; xc = 0.f;
    int f = col - 256;
    tt = f >> 5;
    brow = Bm[i * 32 + (f & 31)];
  }
  float bh[6];
#pragma unroll
  for (int s = 0; s < 6; s++) {
    float hv = (tt == 0) ? Hm[s][0] : ((tt == 1) ? Hm[s][1] : ((tt == 2) ? Hm[s][2] : Hm[s][3]));
    bh[s] = isF ? hv * brow : 0.f;
  }

  float kreg[6];
#pragma unroll
  for (int s = 0; s < 6; s++) kreg[s] = 0.f;

  int j0 = jg * 64;
#pragma unroll 1
  for (int s = 0; s < 6; s++) {
    float xsv = xc;
#pragma unroll
    for (int j = 0; j < 5; j++)
      if (j < s) xsv += AA[s][j] * kreg[j];
    xs4[i][cc] = xsv;
    __syncthreads();
    float acx = 0.f, acy = 0.f, acz = 0.f, acw = 0.f;
#pragma unroll 8
    for (int jj = 0; jj < 64; jj++) {
      int j = j0 + jj;
      float a = AT[(size_t)j * 256 + i];
      float4 xv = *(const float4*)xs4[j];
      acx += a * xv.x;
      acy += a * xv.y;
      acz += a * xv.z;
      acw += a * xv.w;
    }
    part[jg][i] = make_float4(acx, acy, acz, acw);
    __syncthreads();
    float k = bh[s];
#pragma unroll
    for (int g = 0; g < 4; g++) {
      const float* p = (const float*)&part[g][i];
      k += p[cc];
    }
    kreg[s] = k;
  }

  float o = xc;
#pragma unroll
  for (int s = 0; s < 6; s++) o += BB[s] * kreg[s];
  if (!isF) {
    Rout[(size_t)i * 256 + col] = o;
    ushort_t h = bf16_hi(o);
    Rh[(size_t)i * 256 + col] = h;
    Rl[(size_t)i * 256 + col] = bf16_hi(o - bf16_f(h));
  } else {
    int f = col - 256;
    ushort_t h = bf16_hi(o);
    Fh[(size_t)i * 128 + f] = h;
    Fl[(size_t)i * 128 + f] = bf16_hi(o - bf16_f(h));
  }
}

// Top-level starts at stride 512: 64 blocks. X3[k] = x_{512k}.
// 3-term truncated recurrence (exact k<=2; k>=3 drops ||R^1536|| ~ 5e-7).
__global__ __launch_bounds__(256) void top_scan(const float* __restrict__ V3, const float* __restrict__ x0,
                                                const float* __restrict__ R512, float* __restrict__ X3) {
  int k = blockIdx.x, i = threadIdx.x;
  if (k == 0) { X3[i] = x0[i]; return; }
  __shared__ float va[256];
  __shared__ float inner[256];
  if (k == 1) {
    inner[i] = x0[i];
  } else {
    const float* vecA = (k == 2) ? x0 : (V3 + (size_t)(k - 3) * 256);
    va[i] = vecA[i];
    __syncthreads();
    float acc = V3[(size_t)(k - 2) * 256 + i];
    const float* rr = R512 + (size_t)i * 256;
    for (int j = 0; j < 256; j += 4) {
      float4 rv = *(const float4*)(rr + j);
      acc += rv.x * va[j] + rv.y * va[j + 1] + rv.z * va[j + 2] + rv.w * va[j + 3];
    }
    inner[i] = acc;
  }
  __syncthreads();
  float acc2 = V3[(size_t)(k - 1) * 256 + i];
  const float* rr2 = R512 + (size_t)i * 256;
  for (int j = 0; j < 256; j += 4) {
    float4 rv = *(const float4*)(rr2 + j);
    acc2 += rv.x * inner[j] + rv.y * inner[j + 1] + rv.z * inner[j + 2] + rv.w * inner[j + 3];
  }
  X3[(size_t)k * 256 + i] = acc2;
}

extern "C" void kernel_launch(void* const* d_in, const int* in_sizes, int n_in,
                              void* d_out, int out_size, void* d_ws, size_t ws_size,
                              hipStream_t stream) {
  const float* u  = (const float*)d_in[1];
  const float* x0 = (const float*)d_in[2];
  const float* A  = (const float*)d_in[3];
  const float* Bm = (const float*)d_in[4];
  const float* Cm = (const float*)d_in[5];
  const float* Dm = (const float*)d_in[6];
  float* xout = (float*)d_out;                       // [32768][256]
  float* yout = xout + (size_t)TPTS * 256;           // [32768][32]

  char* wsb = (char*)d_ws;
  size_t off = 0;
  auto alloc = [&](size_t bytes) -> void* {
    void* p = (void*)(wsb + off);
    off = (off + bytes + 255) & ~(size_t)255;
    return p;
  };
  float*    Rfp    = (float*)alloc(65536 * 4);
  ushort_t* Rh     = (ushort_t*)alloc(65536 * 2);
  ushort_t* Rl     = (ushort_t*)alloc(65536 * 2);
  float*    PowFp  = (float*)alloc(65536 * 4);       // scratch fp out for R^8/R^64
  ushort_t* R8h    = (ushort_t*)alloc(65536 * 2);
  ushort_t* R8l    = (ushort_t*)alloc(65536 * 2);
  ushort_t* R64h   = (ushort_t*)alloc(65536 * 2);
  ushort_t* R64l   = (ushort_t*)alloc(65536 * 2);
  float*    R512fp = (float*)alloc(65536 * 4);
  ushort_t* R512h  = (ushort_t*)alloc(65536 * 2);
  ushort_t* R512l  = (ushort_t*)alloc(65536 * 2);
  float*    ATm    = (float*)alloc(65536 * 4);
  ushort_t* Fh     = (ushort_t*)alloc(256 * 128 * 2);
  ushort_t* Fl     = (ushort_t*)alloc(256 * 128 * 2);
  float*    V0     = (float*)alloc((size_t)TPTS * 256 * 4);
  float*    V1     = (float*)alloc(4096 * 256 * 4);
  float*    V2     = (float*)alloc(512 * 256 * 4);
  float*    V3     = (float*)alloc(64 * 256 * 4);
  float*    X3     = (float*)alloc(64 * 256 * 4);
  float*    X2     = (float*)alloc(512 * 256 * 4);
  float*    X1     = (float*)alloc(4096 * 256 * 4);
  (void)ws_size; (void)in_sizes; (void)n_in; (void)out_size;

  // 1. A^T; unit responses -> R (fp32 + hi/lo) and Fh/Fl
  transpose_at<<<dim3(16), dim3(256), 0, stream>>>(A, ATm);
  unit_resp<<<dim3(96), dim3(1024), 0, stream>>>(ATm, Bm, Rfp, Rh, Rl, Fh, Fl);

  // 2. pow8 (16 blk) || MFMA drive GEMM (512 blk)
  pow8_gemm<<<dim3(528), dim3(512), 0, stream>>>(Rh, Rl, PowFp, R8h, R8l, u, Fh, Fl, V0);

  // 3. pow64 (16) || reduce0 (256)
  pow64_reduce0<<<dim3(272), dim3(512), 0, stream>>>(R8h, R8l, PowFp, R64h, R64l, Rh, Rl, V0, V1);

  // 4. pow512 (16) || reduce1 (32)
  pow512_reduce1<<<dim3(48), dim3(512), 0, stream>>>(R64h, R64l, R512fp, R512h, R512l, R8h, R8l, V1, V2);

  // 5. reduce2, top starts, expand down
  reduce2_k<<<dim3(4), dim3(512), 0, stream>>>(R64h, R64l, V2, V3);
  top_scan<<<dim3(64), dim3(256), 0, stream>>>(V3, x0, R512fp, X3);
  expand2_k<<<dim3(4), dim3(512), 0, stream>>>(R64h, R64l, X3, V2, X2);
  expand1_k<<<dim3(32), dim3(512), 0, stream>>>(R8h, R8l, X2, V1, X1);

  // 6. expand0, then y (separate launches — fused carried +64MB excess, r8/r9)
  expand0_k<<<dim3(256), dim3(512), 0, stream>>>(Rh, Rl, X1, V0, xout);
  y_kernel<<<dim3(256), dim3(256), 0, stream>>>(xout, u, Cm, Dm, yout);
}

// Round 14
// 287.695 us; speedup vs baseline: 1.0511x; 1.0511x over previous
//
#include <hip/hip_runtime.h>

// Flow_49160195670664: Dopri5 fixed-step integration of dx/dt = A x + B u(t),
// T=32768, N=256, NI=NO=32, dt=1, Hermite-interpolated stage inputs.
// Linear system => x_{n+1} = R x_n + v_n with constant R.
// v4: 4-level blocked parallel scan 8 x 8 x 8 x 64.
// v5: y register-tiled 4x4. v6 (grid barrier): FAILED (~100us/barrier).
// v7/v8: barrier-free fusions; v9: expand0/y unfused (fused carried +64MB).
// v10: drive GEMM on MFMA (314->288). v11 (512thr/2-tile chains): REGRESSED
// 288->302 — per-step cost is LATENCY-bound (2 waves/SIMD hid ds_read/drive
// latency worse), not LDS-throughput-bound; reverted to 16 waves x 1 tile.

#define TPTS 32768

typedef __attribute__((ext_vector_type(8))) short short8;
typedef __attribute__((ext_vector_type(4))) float float4v;
typedef unsigned short ushort_t;

__device__ __forceinline__ ushort_t bf16_hi(float f) {
  unsigned u = __builtin_bit_cast(unsigned, f);
  unsigned r = (u + 0x7FFFu + ((u >> 16) & 1u)) >> 16;
  return (ushort_t)r;
}
__device__ __forceinline__ float bf16_f(ushort_t h) {
  unsigned u = ((unsigned)h) << 16;
  return __builtin_bit_cast(float, u);
}

// ---------------------------------------------------------------------------
// MFMA chain body (device fn). 1024 thr = 16 waves; wave w owns output cols
// [16w,16w+16) as ONE N-tile of mfma_f32_16x16x32_bf16; 16 chains = M-dim.
// bf16 hi/lo split (x*R ~ xh*Rh + xl*Rh + xh*Rl, fp32 acc), 3 independent
// accumulators. V-drive register-prefetched one step ahead. blk is LOGICAL.
// MODE 0: power  (CLEN steps, x0 = I cols; Out = M^CLEN row-major fp32 + h/l)
// MODE 1: reduce (x0 = V row0 of chain, drive rows 1..CLEN-1; Out[chain]=final)
// MODE 2: expand (x0 = X0[chain], drive rows 0..CLEN-2; Out rows chain*CLEN+j)
// Arena: xh @0 (16KB), xl @16K (16KB), hist @32K (16KB MODE0/1, 80KB MODE2).
template <int MODE, int CLEN>
__device__ __forceinline__ void chain_body(char* arena, const ushort_t* Mh, const ushort_t* Ml,
                                           const float* X0, const float* V,
                                           float* Out, ushort_t* OutH, ushort_t* OutL, int blk) {
  constexpr int STEPS = (MODE == 0) ? CLEN : CLEN - 1;
  int t = threadIdx.x;
  int w = t >> 6, l = t & 63;   // w 0..15
  int q = l >> 4, c16 = l & 15;
  int n0 = w * 16;
  ushort_t (*xh)[32][16][8] = reinterpret_cast<ushort_t(*)[32][16][8]>(arena);
  ushort_t (*xl)[32][16][8] = reinterpret_cast<ushort_t(*)[32][16][8]>(arena + 16384);
  float (*hist)[16][256] = reinterpret_cast<float(*)[16][256]>(arena + 32768);
  // B-frags: B[k][n] = M[n][k]; lane holds B[kt*32+q*8+j][n0+c16], j=0..7
  short8 bh[8], bl[8];
#pragma unroll
  for (int kt = 0; kt < 8; kt++) {
    size_t offs = (size_t)(n0 + c16) * 256 + kt * 32 + q * 8;
    bh[kt] = *(const short8*)(Mh + offs);
    bl[kt] = *(const short8*)(Ml + offs);
  }
  // initial x (and row-0 store for MODE 2): 1024 float4, one per thread
  {
    int e = t;
    int c = e >> 6, qq = (e & 63) * 4;
    int cg = blk * 16 + c;
    float4 v4;
    if (MODE == 0) {
      v4 = make_float4(qq == cg ? 1.f : 0.f, qq + 1 == cg ? 1.f : 0.f,
                       qq + 2 == cg ? 1.f : 0.f, qq + 3 == cg ? 1.f : 0.f);
    } else if (MODE == 1) {
      v4 = *(const float4*)(V + (size_t)cg * CLEN * 256 + qq);
    } else {
      v4 = *(const float4*)(X0 + (size_t)cg * 256 + qq);
      *(float4*)(Out + ((size_t)cg * CLEN) * 256 + qq) = v4;
    }
    float vals[4] = {v4.x, v4.y, v4.z, v4.w};
#pragma unroll
    for (int i = 0; i < 4; i++) {
      int n = qq + i;
      ushort_t h = bf16_hi(vals[i]);
      xh[0][n >> 3][c][n & 7] = h;
      xl[0][n >> 3][c][n & 7] = bf16_hi(vals[i] - bf16_f(h));
    }
  }
  // per-lane drive prefetch for step 1 (element r: chain q*4+r, col n0+c16)
  float vnext[4];
  if (MODE != 0) {
#pragma unroll
    for (int r = 0; r < 4; r++) {
      int cg = blk * 16 + q * 4 + r;
      int drow = (MODE == 1) ? 1 : 0;
      vnext[r] = V[((size_t)cg * CLEN + drow) * 256 + n0 + c16];
    }
  }
  __syncthreads();
  for (int s = 1; s <= STEPS; s++) {
    int cur = (s - 1) & 1, nxt = s & 1;
    // MODE 2: flush rows s-4..s-1 (slots row%5) — mod-5 disjoint vs writes
    if (MODE == 2 && s >= 5 && ((s - 1) & 3) == 0) {
      int rbase = s - 4;
      for (int e = t; e < 4096; e += 1024) {
        int slot = e >> 10;
        int rem = e & 1023;
        int c = rem >> 6, qq = (rem & 63) * 4;
        int row = rbase + slot;
        int cg = blk * 16 + c;
        *(float4*)(Out + ((size_t)cg * CLEN + row) * 256 + qq) = *(const float4*)&hist[row % 5][c][qq];
      }
    }
    // drive: consume prefetched, issue next step's loads (hidden under MFMAs)
    float vc[4];
    if (MODE != 0) {
#pragma unroll
      for (int i2 = 0; i2 < 4; i2++) vc[i2] = vnext[i2];
      if (s < STEPS) {
        int drow = (MODE == 1) ? (s + 1) : s;
#pragma unroll
        for (int r = 0; r < 4; r++)
          vnext[r] = V[((size_t)(blk * 16 + q * 4 + r) * CLEN + drow) * 256 + n0 + c16];
      }
    }
    // pin frags: rw asm operand => value must live in VGPRs, reload illegal
#pragma unroll
    for (int kt = 0; kt < 8; kt++) {
      asm volatile("" : "+v"(bh[kt]));
      asm volatile("" : "+v"(bl[kt]));
    }
    float4v aH = {0.f, 0.f, 0.f, 0.f};
    float4v aL = {0.f, 0.f, 0.f, 0.f};
    float4v aC = {0.f, 0.f, 0.f, 0.f};
#pragma unroll
    for (int kt = 0; kt < 8; kt++) {
      short8 ah = *(const short8*)&xh[cur][kt * 4 + q][c16][0];
      short8 al = *(const short8*)&xl[cur][kt * 4 + q][c16][0];
      aH = __builtin_amdgcn_mfma_f32_16x16x32_bf16(ah, bh[kt], aH, 0, 0, 0);
      aL = __builtin_amdgcn_mfma_f32_16x16x32_bf16(al, bh[kt], aL, 0, 0, 0);
      aC = __builtin_amdgcn_mfma_f32_16x16x32_bf16(ah, bl[kt], aC, 0, 0, 0);
    }
    // epilogue: C/D layout chain=(q*4+r), col=c16 (m89-verified)
#pragma unroll
    for (int r = 0; r < 4; r++) {
      int c = q * 4 + r;
      int n = n0 + c16;
      float val = aH[r] + aL[r] + aC[r];
      if (MODE != 0) val += vc[r];
      int cg = blk * 16 + c;
      if (MODE == 2) hist[s % 5][c][n] = val;
      if (MODE == 1 && s == STEPS) Out[(size_t)cg * 256 + n] = val;
      if (MODE == 0 && s == STEPS) {
        ushort_t h2 = bf16_hi(val);
        Out[(size_t)n * 256 + cg] = val;
        OutH[(size_t)n * 256 + cg] = h2;
        OutL[(size_t)n * 256 + cg] = bf16_hi(val - bf16_f(h2));
      }
      ushort_t h = bf16_hi(val);
      xh[nxt][n >> 3][c][n & 7] = h;
      xl[nxt][n >> 3][c][n & 7] = bf16_hi(val - bf16_f(h));
    }
    __syncthreads();
  }
  if (MODE == 2) {   // final rows STEPS-2..STEPS
    for (int e = t; e < 3072; e += 1024) {
      int slot = e >> 10;
      int rem = e & 1023;
      int c = rem >> 6, qq = (rem & 63) * 4;
      int row = (STEPS - 2) + slot;
      int cg = blk * 16 + c;
      *(float4*)(Out + ((size_t)cg * CLEN + row) * 256 + qq) = *(const float4*)&hist[row % 5][c][qq];
    }
  }
}

// ---------------------------------------------------------------------------
// Hermite tap value: row n, k = t*32+c -> {u_n, m_n, u_{n+1}, m_{n+1}}[t][c].
// Row TPTS-1 = 0 (pad).
__device__ __forceinline__ float tap_val(const float* __restrict__ u, int n, int k) {
  if (n >= TPTS - 1) return 0.f;
  int t = k >> 5, c = k & 31;
  if (t == 0) return u[(size_t)n * 32 + c];
  if (t == 2) return u[(size_t)(n + 1) * 32 + c];
  int kk = (t == 1) ? n : n + 1;
  if (kk == 0) return u[32 + c] - u[c];
  if (kk == TPTS - 1) return u[(size_t)(TPTS - 1) * 32 + c] - u[(size_t)(TPTS - 2) * 32 + c];
  return 0.5f * (u[(size_t)(kk + 1) * 32 + c] - u[(size_t)(kk - 1) * 32 + c]);
}

// Drive GEMM on MFMA, 1024 threads: V0[rows g*64..g*64+64)[256] =
// taps[64][128] @ F[128][256], bf16 hi/lo split (taps ~ ah+al, F ~ bh+bl;
// 3 of 4 cross products, fp32 accumulate). 4 groups of 16 rows; per group:
// stage taps to LDS in chain_body's A-frag layout [k>>3][row][k&7]
// (2 taps/thread, packed u32 stores), 12 MFMA per wave. F pre-split to
// Fh/Fl[n][k] (B-frag-ready) by unit_resp. Arena: ah @0 (4KB), al @4K (4KB).
__device__ __forceinline__ void drive_body(char* arena, const float* __restrict__ u,
                                           const ushort_t* __restrict__ Fh,
                                           const ushort_t* __restrict__ Fl,
                                           float* __restrict__ V0, int g) {
  int t = threadIdx.x;
  int w = t >> 6, l = t & 63;
  int q = l >> 4, c16 = l & 15;
  int n0 = w * 16;
  ushort_t (*ah)[16][8] = reinterpret_cast<ushort_t(*)[16][8]>(arena);         // [16][16][8]
  ushort_t (*al)[16][8] = reinterpret_cast<ushort_t(*)[16][8]>(arena + 4096);
  // B-frags: B[k][n] = F[k][n] = Fh/Fl[n*128 + k]; lane needs k=kt*32+q*8+j
  short8 bh[4], bl[4];
#pragma unroll
  for (int kt = 0; kt < 4; kt++) {
    size_t offs = (size_t)(n0 + c16) * 128 + kt * 32 + q * 8;
    bh[kt] = *(const short8*)(Fh + offs);
    bl[kt] = *(const short8*)(Fl + offs);
  }
  int rowbase = g * 64;
  int srow = t >> 6;      // staging row 0..15
  int k0 = l * 2;         // staging k 0..126 (even; k0,k0+1 same 8-group)
  for (int grp = 0; grp < 4; grp++) {
    int rb = rowbase + grp * 16;
    float v0 = tap_val(u, rb + srow, k0);
    float v1 = tap_val(u, rb + srow, k0 + 1);
    ushort_t h0 = bf16_hi(v0), h1 = bf16_hi(v1);
    ushort_t lo0 = bf16_hi(v0 - bf16_f(h0)), lo1 = bf16_hi(v1 - bf16_f(h1));
    *(unsigned*)&ah[k0 >> 3][srow][k0 & 7] = (unsigned)h0 | ((unsigned)h1 << 16);
    *(unsigned*)&al[k0 >> 3][srow][k0 & 7] = (unsigned)lo0 | ((unsigned)lo1 << 16);
    __syncthreads();
    float4v aH = {0.f, 0.f, 0.f, 0.f};
    float4v aL = {0.f, 0.f, 0.f, 0.f};
    float4v aC = {0.f, 0.f, 0.f, 0.f};
#pragma unroll
    for (int kt = 0; kt < 4; kt++) {
      short8 a_h = *(const short8*)&ah[kt * 4 + q][c16][0];
      short8 a_l = *(const short8*)&al[kt * 4 + q][c16][0];
      aH = __builtin_amdgcn_mfma_f32_16x16x32_bf16(a_h, bh[kt], aH, 0, 0, 0);
      aL = __builtin_amdgcn_mfma_f32_16x16x32_bf16(a_l, bh[kt], aL, 0, 0, 0);
      aC = __builtin_amdgcn_mfma_f32_16x16x32_bf16(a_h, bl[kt], aC, 0, 0, 0);
    }
    // C/D: row = q*4+r, col = c16 (same mapping as chain_body epilogue)
#pragma unroll
    for (int r = 0; r < 4; r++) {
      int row = rb + q * 4 + r;
      V0[(size_t)row * 256 + n0 + c16] = aH[r] + aL[r] + aC[r];
    }
    __syncthreads();
  }
}

// ---------------------------------------------------------------------------
// Fused kernels (disjoint block ranges; no cross-block dependencies in-kernel)
__global__ __launch_bounds__(1024, 4) void pow8_gemm(const ushort_t* Rh, const ushort_t* Rl,
                                                     float* PowFp, ushort_t* R8h, ushort_t* R8l,
                                                     const float* u, const ushort_t* Fh,
                                                     const ushort_t* Fl, float* V0) {
  __shared__ __attribute__((aligned(16))) char arena[49152];
  int blk = blockIdx.x;
  if (blk < 16)
    chain_body<0, 8>(arena, Rh, Rl, nullptr, nullptr, PowFp, R8h, R8l, blk);
  else
    drive_body(arena, u, Fh, Fl, V0, blk - 16);
}

__global__ __launch_bounds__(1024, 4) void pow64_reduce0(const ushort_t* R8h, const ushort_t* R8l,
                                                         float* PowFp, ushort_t* R64h, ushort_t* R64l,
                                                         const ushort_t* Rh, const ushort_t* Rl,
                                                         const float* V0, float* V1) {
  __shared__ __attribute__((aligned(16))) char arena[49152];
  int blk = blockIdx.x;
  if (blk < 16)
    chain_body<0, 8>(arena, R8h, R8l, nullptr, nullptr, PowFp, R64h, R64l, blk);
  else
    chain_body<1, 8>(arena, Rh, Rl, nullptr, V0, V1, nullptr, nullptr, blk - 16);
}

__global__ __launch_bounds__(1024, 4) void pow512_reduce1(const ushort_t* R64h, const ushort_t* R64l,
                                                          float* R512fp, ushort_t* R512h, ushort_t* R512l,
                                                          const ushort_t* R8h, const ushort_t* R8l,
                                                          const float* V1, float* V2) {
  __shared__ __attribute__((aligned(16))) char arena[49152];
  int blk = blockIdx.x;
  if (blk < 16)
    chain_body<0, 8>(arena, R64h, R64l, nullptr, nullptr, R512fp, R512h, R512l, blk);
  else
    chain_body<1, 8>(arena, R8h, R8l, nullptr, V1, V2, nullptr, nullptr, blk - 16);
}

__global__ __launch_bounds__(1024, 4) void reduce2_k(const ushort_t* R64h, const ushort_t* R64l,
                                                     const float* V2, float* V3) {
  __shared__ __attribute__((aligned(16))) char arena[49152];
  chain_body<1, 8>(arena, R64h, R64l, nullptr, V2, V3, nullptr, nullptr, blockIdx.x);
}

__global__ __launch_bounds__(1024, 4) void expand2_k(const ushort_t* R64h, const ushort_t* R64l,
                                                     const float* X3, const float* V2, float* X2) {
  __shared__ __attribute__((aligned(16))) char arena[114688];
  chain_body<2, 8>(arena, R64h, R64l, X3, V2, X2, nullptr, nullptr, blockIdx.x);
}

__global__ __launch_bounds__(1024, 4) void expand1_k(const ushort_t* R8h, const ushort_t* R8l,
                                                     const float* X2, const float* V1, float* X1) {
  __shared__ __attribute__((aligned(16))) char arena[114688];
  chain_body<2, 8>(arena, R8h, R8l, X2, V1, X1, nullptr, nullptr, blockIdx.x);
}

__global__ __launch_bounds__(1024, 4) void expand0_k(const ushort_t* Rh, const ushort_t* Rl,
                                                     const float* X1, const float* V0, float* xout) {
  __shared__ __attribute__((aligned(16))) char arena[114688];
  chain_body<2, 8>(arena, Rh, Rl, X1, V0, xout, nullptr, nullptr, blockIdx.x);
}

// ---------------------------------------------------------------------------
// y = x @ C^T + u @ D^T. Register-tiled 4x4 (v5-verified). 256 blocks x 256
// thr; thread (rt,ct) computes rows n0+rt*4+0..3 x cols ct*4+0..3. C/D stored
// TRANSPOSED in LDS (conflict-free); x read straight from global (L2/L3).
__global__ __launch_bounds__(256) void y_kernel(const float* __restrict__ x, const float* __restrict__ u,
                                                const float* __restrict__ Cm, const float* __restrict__ Dm,
                                                float* __restrict__ y) {
  __shared__ float CsT[256][36];
  __shared__ float DsT[32][36];
  int tid = threadIdx.x;
  for (int k = tid; k < 8192; k += 256) CsT[k & 255][k >> 8] = Cm[k];
  for (int k = tid; k < 1024; k += 256) DsT[k & 31][k >> 5] = Dm[k];
  __syncthreads();
  int rt = tid >> 3, ct = tid & 7;
  int n0 = blockIdx.x * 128 + rt * 4;
  int o0 = ct * 4;
  float acc[4][4] = {{0.f}};
#pragma unroll 4
  for (int i = 0; i < 256; i += 4) {
    float4 cv0 = *(const float4*)&CsT[i + 0][o0];
    float4 cv1 = *(const float4*)&CsT[i + 1][o0];
    float4 cv2 = *(const float4*)&CsT[i + 2][o0];
    float4 cv3 = *(const float4*)&CsT[i + 3][o0];
#pragma unroll
    for (int r = 0; r < 4; r++) {
      float4 xv = *(const float4*)(x + (size_t)(n0 + r) * 256 + i);
      acc[r][0] += xv.x * cv0.x + xv.y * cv1.x + xv.z * cv2.x + xv.w * cv3.x;
      acc[r][1] += xv.x * cv0.y + xv.y * cv1.y + xv.z * cv2.y + xv.w * cv3.y;
      acc[r][2] += xv.x * cv0.z + xv.y * cv1.z + xv.z * cv2.z + xv.w * cv3.z;
      acc[r][3] += xv.x * cv0.w + xv.y * cv1.w + xv.z * cv2.w + xv.w * cv3.w;
    }
  }
#pragma unroll
  for (int i = 0; i < 32; i += 4) {
    float4 dv0 = *(const float4*)&DsT[i + 0][o0];
    float4 dv1 = *(const float4*)&DsT[i + 1][o0];
    float4 dv2 = *(const float4*)&DsT[i + 2][o0];
    float4 dv3 = *(const float4*)&DsT[i + 3][o0];
#pragma unroll
    for (int r = 0; r < 4; r++) {
      float4 uv = *(const float4*)(u + (size_t)(n0 + r) * 32 + i);
      acc[r][0] += uv.x * dv0.x + uv.y * dv1.x + uv.z * dv2.x + uv.w * dv3.x;
      acc[r][1] += uv.x * dv0.y + uv.y * dv1.y + uv.z * dv2.y + uv.w * dv3.y;
      acc[r][2] += uv.x * dv0.z + uv.y * dv1.z + uv.z * dv2.z + uv.w * dv3.z;
      acc[r][3] += uv.x * dv0.w + uv.y * dv1.w + uv.z * dv2.w + uv.w * dv3.w;
    }
  }
#pragma unroll
  for (int r = 0; r < 4; r++)
    *(float4*)(y + (size_t)(n0 + r) * 32 + o0) =
        make_float4(acc[r][0], acc[r][1], acc[r][2], acc[r][3]);
}

// ---------------------------------------------------------------------------
// AT = A^T (256x256)
__global__ __launch_bounds__(256) void transpose_at(const float* __restrict__ A, float* __restrict__ AT) {
  __shared__ float tile[64][65];
  int bx = blockIdx.x & 3, by = blockIdx.x >> 2;
  int r0 = by * 64, c0 = bx * 64;
  int t = threadIdx.x;
  int lr = t >> 4, lc = (t & 15) * 4;
  for (int rr = lr; rr < 64; rr += 16) {
    float4 v = *(const float4*)(A + (size_t)(r0 + rr) * 256 + c0 + lc);
    tile[rr][lc + 0] = v.x; tile[rr][lc + 1] = v.y; tile[rr][lc + 2] = v.z; tile[rr][lc + 3] = v.w;
  }
  __syncthreads();
  for (int rr = lr; rr < 64; rr += 16) {
    float4 v = make_float4(tile[lc + 0][rr], tile[lc + 1][rr], tile[lc + 2][rr], tile[lc + 3][rr]);
    *(float4*)(AT + (size_t)(c0 + rr) * 256 + r0 + lc) = v;
  }
}

// Unit responses through one Dopri5 step: cols 0..255 -> R fp32 + bf16 hi/lo
// split; cols 256..383 -> Hermite-folded tap matrices, bf16 hi/lo split,
// stored TRANSPOSED as Fh/Fl[n][k] (B-frag-ready for drive_body).
// 1024 threads = 4 j-groups x 256 rows; 4-way split-K with LDS reduce.
__global__ __launch_bounds__(1024) void unit_resp(const float* __restrict__ AT,
                                                  const float* __restrict__ Bm,
                                                  float* __restrict__ Rout,
                                                  ushort_t* __restrict__ Rh,
                                                  ushort_t* __restrict__ Rl,
                                                  ushort_t* __restrict__ Fh,
                                                  ushort_t* __restrict__ Fl) {
  int blk = blockIdx.x;
  int tid = threadIdx.x;
  int jg = tid >> 8;   // j-group 0..3, also the owned column index cc
  int i = tid & 255;   // output row
  int cc = jg;
  int col = blk * 4 + cc;

  __shared__ float xs4[256][4];
  __shared__ float4 part[4][256];

  const float AA[6][5] = {
      {0.f, 0.f, 0.f, 0.f, 0.f},
      {0.2f, 0.f, 0.f, 0.f, 0.f},
      {3.f / 40.f, 9.f / 40.f, 0.f, 0.f, 0.f},
      {44.f / 45.f, -56.f / 15.f, 32.f / 9.f, 0.f, 0.f},
      {19372.f / 6561.f, -25360.f / 2187.f, 64448.f / 6561.f, -212.f / 729.f, 0.f},
      {9017.f / 3168.f, -355.f / 33.f, 46732.f / 5247.f, 49.f / 176.f, -5103.f / 18656.f}};
  const float BB[6] = {35.f / 384.f, 0.f, 500.f / 1113.f, 125.f / 192.f, -2187.f / 6784.f, 11.f / 84.f};
  const float sv[6] = {0.f, 0.2f, 0.3f, 0.8f, 8.f / 9.f, 1.f};
  float Hm[6][4];
#pragma unroll
  for (int s = 0; s < 6; s++) {
    float ss = sv[s], s2 = ss * ss, s3 = s2 * ss;
    Hm[s][0] = 2.f * s3 - 3.f * s2 + 1.f;
    Hm[s][1] = s3 - 2.f * s2 + ss;
    Hm[s][2] = -2.f * s3 + 3.f * s2;
    Hm[s][3] = s3 - s2;
  }

  // owned-column metadata
  int isF, tt;
  float brow, xc;
  if (col < 256) {
    isF = 0; tt = 0; brow = 0.f;
    xc = (i == col) ? 1.f : 0.f;
  } else {
    isF = 1; xc = 0.f;
    int f = col - 256;
    tt = f >> 5;
    brow = Bm[i * 32 + (f & 31)];
  }
  float bh[6];
#pragma unroll
  for (int s = 0; s < 6; s++) {
    float hv = (tt == 0) ? Hm[s][0] : ((tt == 1) ? Hm[s][1] : ((tt == 2) ? Hm[s][2] : Hm[s][3]));
    bh[s] = isF ? hv * brow : 0.f;
  }

  float kreg[6];
#pragma unroll
  for (int s = 0; s < 6; s++) kreg[s] = 0.f;

  int j0 = jg * 64;
#pragma unroll 1
  for (int s = 0; s < 6; s++) {
    float xsv = xc;
#pragma unroll
    for (int j = 0; j < 5; j++)
      if (j < s) xsv += AA[s][j] * kreg[j];
    xs4[i][cc] = xsv;
    __syncthreads();
    float acx = 0.f, acy = 0.f, acz = 0.f, acw = 0.f;
#pragma unroll 8
    for (int jj = 0; jj < 64; jj++) {
      int j = j0 + jj;
      float a = AT[(size_t)j * 256 + i];
      float4 xv = *(const float4*)xs4[j];
      acx += a * xv.x;
      acy += a * xv.y;
      acz += a * xv.z;
      acw += a * xv.w;
    }
    part[jg][i] = make_float4(acx, acy, acz, acw);
    __syncthreads();
    float k = bh[s];
#pragma unroll
    for (int g = 0; g < 4; g++) {
      const float* p = (const float*)&part[g][i];
      k += p[cc];
    }
    kreg[s] = k;
  }

  float o = xc;
#pragma unroll
  for (int s = 0; s < 6; s++) o += BB[s] * kreg[s];
  if (!isF) {
    Rout[(size_t)i * 256 + col] = o;
    ushort_t h = bf16_hi(o);
    Rh[(size_t)i * 256 + col] = h;
    Rl[(size_t)i * 256 + col] = bf16_hi(o - bf16_f(h));
  } else {
    int f = col - 256;
    ushort_t h = bf16_hi(o);
    Fh[(size_t)i * 128 + f] = h;
    Fl[(size_t)i * 128 + f] = bf16_hi(o - bf16_f(h));
  }
}

// Top-level starts at stride 512: 64 blocks. X3[k] = x_{512k}.
// 3-term truncated recurrence (exact k<=2; k>=3 drops ||R^1536|| ~ 5e-7).
__global__ __launch_bounds__(256) void top_scan(const float* __restrict__ V3, const float* __restrict__ x0,
                                                const float* __restrict__ R512, float* __restrict__ X3) {
  int k = blockIdx.x, i = threadIdx.x;
  if (k == 0) { X3[i] = x0[i]; return; }
  __shared__ float va[256];
  __shared__ float inner[256];
  if (k == 1) {
    inner[i] = x0[i];
  } else {
    const float* vecA = (k == 2) ? x0 : (V3 + (size_t)(k - 3) * 256);
    va[i] = vecA[i];
    __syncthreads();
    float acc = V3[(size_t)(k - 2) * 256 + i];
    const float* rr = R512 + (size_t)i * 256;
    for (int j = 0; j < 256; j += 4) {
      float4 rv = *(const float4*)(rr + j);
      acc += rv.x * va[j] + rv.y * va[j + 1] + rv.z * va[j + 2] + rv.w * va[j + 3];
    }
    inner[i] = acc;
  }
  __syncthreads();
  float acc2 = V3[(size_t)(k - 1) * 256 + i];
  const float* rr2 = R512 + (size_t)i * 256;
  for (int j = 0; j < 256; j += 4) {
    float4 rv = *(const float4*)(rr2 + j);
    acc2 += rv.x * inner[j] + rv.y * inner[j + 1] + rv.z * inner[j + 2] + rv.w * inner[j + 3];
  }
  X3[(size_t)k * 256 + i] = acc2;
}

extern "C" void kernel_launch(void* const* d_in, const int* in_sizes, int n_in,
                              void* d_out, int out_size, void* d_ws, size_t ws_size,
                              hipStream_t stream) {
  const float* u  = (const float*)d_in[1];
  const float* x0 = (const float*)d_in[2];
  const float* A  = (const float*)d_in[3];
  const float* Bm = (const float*)d_in[4];
  const float* Cm = (const float*)d_in[5];
  const float* Dm = (const float*)d_in[6];
  float* xout = (float*)d_out;                       // [32768][256]
  float* yout = xout + (size_t)TPTS * 256;           // [32768][32]

  char* wsb = (char*)d_ws;
  size_t off = 0;
  auto alloc = [&](size_t bytes) -> void* {
    void* p = (void*)(wsb + off);
    off = (off + bytes + 255) & ~(size_t)255;
    return p;
  };
  float*    Rfp    = (float*)alloc(65536 * 4);
  ushort_t* Rh     = (ushort_t*)alloc(65536 * 2);
  ushort_t* Rl     = (ushort_t*)alloc(65536 * 2);
  float*    PowFp  = (float*)alloc(65536 * 4);       // scratch fp out for R^8/R^64
  ushort_t* R8h    = (ushort_t*)alloc(65536 * 2);
  ushort_t* R8l    = (ushort_t*)alloc(65536 * 2);
  ushort_t* R64h   = (ushort_t*)alloc(65536 * 2);
  ushort_t* R64l   = (ushort_t*)alloc(65536 * 2);
  float*    R512fp = (float*)alloc(65536 * 4);
  ushort_t* R512h  = (ushort_t*)alloc(65536 * 2);
  ushort_t* R512l  = (ushort_t*)alloc(65536 * 2);
  float*    ATm    = (float*)alloc(65536 * 4);
  ushort_t* Fh     = (ushort_t*)alloc(256 * 128 * 2);
  ushort_t* Fl     = (ushort_t*)alloc(256 * 128 * 2);
  float*    V0     = (float*)alloc((size_t)TPTS * 256 * 4);
  float*    V1     = (float*)alloc(4096 * 256 * 4);
  float*    V2     = (float*)alloc(512 * 256 * 4);
  float*    V3     = (float*)alloc(64 * 256 * 4);
  float*    X3     = (float*)alloc(64 * 256 * 4);
  float*    X2     = (float*)alloc(512 * 256 * 4);
  float*    X1     = (float*)alloc(4096 * 256 * 4);
  (void)ws_size; (void)in_sizes; (void)n_in; (void)out_size;

  // 1. A^T; unit responses -> R (fp32 + hi/lo) and Fh/Fl
  transpose_at<<<dim3(16), dim3(256), 0, stream>>>(A, ATm);
  unit_resp<<<dim3(96), dim3(1024), 0, stream>>>(ATm, Bm, Rfp, Rh, Rl, Fh, Fl);

  // 2. pow8 (16 blk) || MFMA drive GEMM (512 blk) — independent given unit_resp
  pow8_gemm<<<dim3(528), dim3(1024), 0, stream>>>(Rh, Rl, PowFp, R8h, R8l, u, Fh, Fl, V0);

  // 3. pow64 (16) || reduce0 (256)
  pow64_reduce0<<<dim3(272), dim3(1024), 0, stream>>>(R8h, R8l, PowFp, R64h, R64l, Rh, Rl, V0, V1);

  // 4. pow512 (16) || reduce1 (32)
  pow512_reduce1<<<dim3(48), dim3(1024), 0, stream>>>(R64h, R64l, R512fp, R512h, R512l, R8h, R8l, V1, V2);

  // 5. reduce2, top starts, expand down
  reduce2_k<<<dim3(4), dim3(1024), 0, stream>>>(R64h, R64l, V2, V3);
  top_scan<<<dim3(64), dim3(256), 0, stream>>>(V3, x0, R512fp, X3);
  expand2_k<<<dim3(4), dim3(1024), 0, stream>>>(R64h, R64l, X3, V2, X2);
  expand1_k<<<dim3(32), dim3(1024), 0, stream>>>(R8h, R8l, X2, V1, X1);

  // 6. expand0, then y (separate launches — fused version carried +64MB
  //    structural excess traffic, r8/r9 counters)
  expand0_k<<<dim3(256), dim3(1024), 0, stream>>>(Rh, Rl, X1, V0, xout);
  y_kernel<<<dim3(256), dim3(256), 0, stream>>>(xout, u, Cm, Dm, yout);
}

// Round 15
// 274.318 us; speedup vs baseline: 1.1024x; 1.0488x over previous
//
#include <hip/hip_runtime.h>

// Flow_49160195670664: Dopri5 fixed-step integration of dx/dt = A x + B u(t),
// T=32768, N=256, NI=NO=32, dt=1, Hermite-interpolated stage inputs.
// Linear system => x_{n+1} = R x_n + v_n with constant R.
// v5: y register-tiled. v6 (grid barrier): FAILED (~100us/barrier).
// v7/v8/v9: barrier-free fusions, expand0/y unfused. v10: drive on MFMA (288).
// v11 (512thr chains): REGRESSED (latency-bound, not LDS-BW) -> reverted.
// v12: tree 8x8x8x64 -> 8x8x4x128: 66 -> 54 sequential chain steps
// (powers 8+8+4, reduces 7+7+3, expands 7+7+3); top level 128 starts with
// R^256, 4-term truncated recurrence (drops ||R^1024||*X ~ 6e-5 — same bound
// as the original design; exact for k<=3). Launch count unchanged.

#define TPTS 32768

typedef __attribute__((ext_vector_type(8))) short short8;
typedef __attribute__((ext_vector_type(4))) float float4v;
typedef unsigned short ushort_t;

__device__ __forceinline__ ushort_t bf16_hi(float f) {
  unsigned u = __builtin_bit_cast(unsigned, f);
  unsigned r = (u + 0x7FFFu + ((u >> 16) & 1u)) >> 16;
  return (ushort_t)r;
}
__device__ __forceinline__ float bf16_f(ushort_t h) {
  unsigned u = ((unsigned)h) << 16;
  return __builtin_bit_cast(float, u);
}

// ---------------------------------------------------------------------------
// MFMA chain body (device fn). 1024 thr = 16 waves; wave w owns output cols
// [16w,16w+16) as ONE N-tile of mfma_f32_16x16x32_bf16; 16 chains = M-dim.
// bf16 hi/lo split (x*R ~ xh*Rh + xl*Rh + xh*Rl, fp32 acc), 3 independent
// accumulators. V-drive register-prefetched one step ahead. blk is LOGICAL.
// MODE 0: power  (CLEN steps, x0 = I cols; Out = M^CLEN row-major fp32 + h/l)
// MODE 1: reduce (x0 = V row0 of chain, drive rows 1..CLEN-1; Out[chain]=final)
// MODE 2: expand (x0 = X0[chain], drive rows 0..CLEN-2; Out rows chain*CLEN+j)
// Arena: xh @0 (16KB), xl @16K (16KB), hist @32K (16KB MODE0/1, 80KB MODE2).
template <int MODE, int CLEN>
__device__ __forceinline__ void chain_body(char* arena, const ushort_t* Mh, const ushort_t* Ml,
                                           const float* X0, const float* V,
                                           float* Out, ushort_t* OutH, ushort_t* OutL, int blk) {
  constexpr int STEPS = (MODE == 0) ? CLEN : CLEN - 1;
  int t = threadIdx.x;
  int w = t >> 6, l = t & 63;   // w 0..15
  int q = l >> 4, c16 = l & 15;
  int n0 = w * 16;
  ushort_t (*xh)[32][16][8] = reinterpret_cast<ushort_t(*)[32][16][8]>(arena);
  ushort_t (*xl)[32][16][8] = reinterpret_cast<ushort_t(*)[32][16][8]>(arena + 16384);
  float (*hist)[16][256] = reinterpret_cast<float(*)[16][256]>(arena + 32768);
  // B-frags: B[k][n] = M[n][k]; lane holds B[kt*32+q*8+j][n0+c16], j=0..7
  short8 bh[8], bl[8];
#pragma unroll
  for (int kt = 0; kt < 8; kt++) {
    size_t offs = (size_t)(n0 + c16) * 256 + kt * 32 + q * 8;
    bh[kt] = *(const short8*)(Mh + offs);
    bl[kt] = *(const short8*)(Ml + offs);
  }
  // initial x (and row-0 store for MODE 2): 1024 float4, one per thread
  {
    int e = t;
    int c = e >> 6, qq = (e & 63) * 4;
    int cg = blk * 16 + c;
    float4 v4;
    if (MODE == 0) {
      v4 = make_float4(qq == cg ? 1.f : 0.f, qq + 1 == cg ? 1.f : 0.f,
                       qq + 2 == cg ? 1.f : 0.f, qq + 3 == cg ? 1.f : 0.f);
    } else if (MODE == 1) {
      v4 = *(const float4*)(V + (size_t)cg * CLEN * 256 + qq);
    } else {
      v4 = *(const float4*)(X0 + (size_t)cg * 256 + qq);
      *(float4*)(Out + ((size_t)cg * CLEN) * 256 + qq) = v4;
    }
    float vals[4] = {v4.x, v4.y, v4.z, v4.w};
#pragma unroll
    for (int i = 0; i < 4; i++) {
      int n = qq + i;
      ushort_t h = bf16_hi(vals[i]);
      xh[0][n >> 3][c][n & 7] = h;
      xl[0][n >> 3][c][n & 7] = bf16_hi(vals[i] - bf16_f(h));
    }
  }
  // per-lane drive prefetch for step 1 (element r: chain q*4+r, col n0+c16)
  float vnext[4];
  if (MODE != 0) {
#pragma unroll
    for (int r = 0; r < 4; r++) {
      int cg = blk * 16 + q * 4 + r;
      int drow = (MODE == 1) ? 1 : 0;
      vnext[r] = V[((size_t)cg * CLEN + drow) * 256 + n0 + c16];
    }
  }
  __syncthreads();
  for (int s = 1; s <= STEPS; s++) {
    int cur = (s - 1) & 1, nxt = s & 1;
    // MODE 2: flush rows s-4..s-1 (slots row%5) — mod-5 disjoint vs writes
    if (MODE == 2 && s >= 5 && ((s - 1) & 3) == 0) {
      int rbase = s - 4;
      for (int e = t; e < 4096; e += 1024) {
        int slot = e >> 10;
        int rem = e & 1023;
        int c = rem >> 6, qq = (rem & 63) * 4;
        int row = rbase + slot;
        int cg = blk * 16 + c;
        *(float4*)(Out + ((size_t)cg * CLEN + row) * 256 + qq) = *(const float4*)&hist[row % 5][c][qq];
      }
    }
    // drive: consume prefetched, issue next step's loads (hidden under MFMAs)
    float vc[4];
    if (MODE != 0) {
#pragma unroll
      for (int i2 = 0; i2 < 4; i2++) vc[i2] = vnext[i2];
      if (s < STEPS) {
        int drow = (MODE == 1) ? (s + 1) : s;
#pragma unroll
        for (int r = 0; r < 4; r++)
          vnext[r] = V[((size_t)(blk * 16 + q * 4 + r) * CLEN + drow) * 256 + n0 + c16];
      }
    }
    // pin frags: rw asm operand => value must live in VGPRs, reload illegal
#pragma unroll
    for (int kt = 0; kt < 8; kt++) {
      asm volatile("" : "+v"(bh[kt]));
      asm volatile("" : "+v"(bl[kt]));
    }
    float4v aH = {0.f, 0.f, 0.f, 0.f};
    float4v aL = {0.f, 0.f, 0.f, 0.f};
    float4v aC = {0.f, 0.f, 0.f, 0.f};
#pragma unroll
    for (int kt = 0; kt < 8; kt++) {
      short8 ah = *(const short8*)&xh[cur][kt * 4 + q][c16][0];
      short8 al = *(const short8*)&xl[cur][kt * 4 + q][c16][0];
      aH = __builtin_amdgcn_mfma_f32_16x16x32_bf16(ah, bh[kt], aH, 0, 0, 0);
      aL = __builtin_amdgcn_mfma_f32_16x16x32_bf16(al, bh[kt], aL, 0, 0, 0);
      aC = __builtin_amdgcn_mfma_f32_16x16x32_bf16(ah, bl[kt], aC, 0, 0, 0);
    }
    // epilogue: C/D layout chain=(q*4+r), col=c16 (m89-verified)
#pragma unroll
    for (int r = 0; r < 4; r++) {
      int c = q * 4 + r;
      int n = n0 + c16;
      float val = aH[r] + aL[r] + aC[r];
      if (MODE != 0) val += vc[r];
      int cg = blk * 16 + c;
      if (MODE == 2) hist[s % 5][c][n] = val;
      if (MODE == 1 && s == STEPS) Out[(size_t)cg * 256 + n] = val;
      if (MODE == 0 && s == STEPS) {
        ushort_t h2 = bf16_hi(val);
        Out[(size_t)n * 256 + cg] = val;
        OutH[(size_t)n * 256 + cg] = h2;
        OutL[(size_t)n * 256 + cg] = bf16_hi(val - bf16_f(h2));
      }
      ushort_t h = bf16_hi(val);
      xh[nxt][n >> 3][c][n & 7] = h;
      xl[nxt][n >> 3][c][n & 7] = bf16_hi(val - bf16_f(h));
    }
    __syncthreads();
  }
  if (MODE == 2) {   // final rows STEPS-2..STEPS
    for (int e = t; e < 3072; e += 1024) {
      int slot = e >> 10;
      int rem = e & 1023;
      int c = rem >> 6, qq = (rem & 63) * 4;
      int row = (STEPS - 2) + slot;
      int cg = blk * 16 + c;
      *(float4*)(Out + ((size_t)cg * CLEN + row) * 256 + qq) = *(const float4*)&hist[row % 5][c][qq];
    }
  }
}

// ---------------------------------------------------------------------------
// Hermite tap value: row n, k = t*32+c -> {u_n, m_n, u_{n+1}, m_{n+1}}[t][c].
// Row TPTS-1 = 0 (pad).
__device__ __forceinline__ float tap_val(const float* __restrict__ u, int n, int k) {
  if (n >= TPTS - 1) return 0.f;
  int t = k >> 5, c = k & 31;
  if (t == 0) return u[(size_t)n * 32 + c];
  if (t == 2) return u[(size_t)(n + 1) * 32 + c];
  int kk = (t == 1) ? n : n + 1;
  if (kk == 0) return u[32 + c] - u[c];
  if (kk == TPTS - 1) return u[(size_t)(TPTS - 1) * 32 + c] - u[(size_t)(TPTS - 2) * 32 + c];
  return 0.5f * (u[(size_t)(kk + 1) * 32 + c] - u[(size_t)(kk - 1) * 32 + c]);
}

// Drive GEMM on MFMA, 1024 threads: V0[rows g*64..g*64+64)[256] =
// taps[64][128] @ F[128][256], bf16 hi/lo split, 12 MFMA per wave per group.
// Arena: ah @0 (4KB), al @4K (4KB).
__device__ __forceinline__ void drive_body(char* arena, const float* __restrict__ u,
                                           const ushort_t* __restrict__ Fh,
                                           const ushort_t* __restrict__ Fl,
                                           float* __restrict__ V0, int g) {
  int t = threadIdx.x;
  int w = t >> 6, l = t & 63;
  int q = l >> 4, c16 = l & 15;
  int n0 = w * 16;
  ushort_t (*ah)[16][8] = reinterpret_cast<ushort_t(*)[16][8]>(arena);         // [16][16][8]
  ushort_t (*al)[16][8] = reinterpret_cast<ushort_t(*)[16][8]>(arena + 4096);
  // B-frags: B[k][n] = F[k][n] = Fh/Fl[n*128 + k]; lane needs k=kt*32+q*8+j
  short8 bh[4], bl[4];
#pragma unroll
  for (int kt = 0; kt < 4; kt++) {
    size_t offs = (size_t)(n0 + c16) * 128 + kt * 32 + q * 8;
    bh[kt] = *(const short8*)(Fh + offs);
    bl[kt] = *(const short8*)(Fl + offs);
  }
  int rowbase = g * 64;
  int srow = t >> 6;      // staging row 0..15
  int k0 = l * 2;         // staging k 0..126 (even; k0,k0+1 same 8-group)
  for (int grp = 0; grp < 4; grp++) {
    int rb = rowbase + grp * 16;
    float v0 = tap_val(u, rb + srow, k0);
    float v1 = tap_val(u, rb + srow, k0 + 1);
    ushort_t h0 = bf16_hi(v0), h1 = bf16_hi(v1);
    ushort_t lo0 = bf16_hi(v0 - bf16_f(h0)), lo1 = bf16_hi(v1 - bf16_f(h1));
    *(unsigned*)&ah[k0 >> 3][srow][k0 & 7] = (unsigned)h0 | ((unsigned)h1 << 16);
    *(unsigned*)&al[k0 >> 3][srow][k0 & 7] = (unsigned)lo0 | ((unsigned)lo1 << 16);
    __syncthreads();
    float4v aH = {0.f, 0.f, 0.f, 0.f};
    float4v aL = {0.f, 0.f, 0.f, 0.f};
    float4v aC = {0.f, 0.f, 0.f, 0.f};
#pragma unroll
    for (int kt = 0; kt < 4; kt++) {
      short8 a_h = *(const short8*)&ah[kt * 4 + q][c16][0];
      short8 a_l = *(const short8*)&al[kt * 4 + q][c16][0];
      aH = __builtin_amdgcn_mfma_f32_16x16x32_bf16(a_h, bh[kt], aH, 0, 0, 0);
      aL = __builtin_amdgcn_mfma_f32_16x16x32_bf16(a_l, bh[kt], aL, 0, 0, 0);
      aC = __builtin_amdgcn_mfma_f32_16x16x32_bf16(a_h, bl[kt], aC, 0, 0, 0);
    }
    // C/D: row = q*4+r, col = c16 (same mapping as chain_body epilogue)
#pragma unroll
    for (int r = 0; r < 4; r++) {
      int row = rb + q * 4 + r;
      V0[(size_t)row * 256 + n0 + c16] = aH[r] + aL[r] + aC[r];
    }
    __syncthreads();
  }
}

// ---------------------------------------------------------------------------
// Fused kernels (disjoint block ranges; no cross-block dependencies in-kernel)
__global__ __launch_bounds__(1024, 4) void pow8_gemm(const ushort_t* Rh, const ushort_t* Rl,
                                                     float* PowFp, ushort_t* R8h, ushort_t* R8l,
                                                     const float* u, const ushort_t* Fh,
                                                     const ushort_t* Fl, float* V0) {
  __shared__ __attribute__((aligned(16))) char arena[49152];
  int blk = blockIdx.x;
  if (blk < 16)
    chain_body<0, 8>(arena, Rh, Rl, nullptr, nullptr, PowFp, R8h, R8l, blk);
  else
    drive_body(arena, u, Fh, Fl, V0, blk - 16);
}

__global__ __launch_bounds__(1024, 4) void pow64_reduce0(const ushort_t* R8h, const ushort_t* R8l,
                                                         float* PowFp, ushort_t* R64h, ushort_t* R64l,
                                                         const ushort_t* Rh, const ushort_t* Rl,
                                                         const float* V0, float* V1) {
  __shared__ __attribute__((aligned(16))) char arena[49152];
  int blk = blockIdx.x;
  if (blk < 16)
    chain_body<0, 8>(arena, R8h, R8l, nullptr, nullptr, PowFp, R64h, R64l, blk);
  else
    chain_body<1, 8>(arena, Rh, Rl, nullptr, V0, V1, nullptr, nullptr, blk - 16);
}

// pow256 = (R^64)^4 (CLEN=4) || reduce1 (CLEN=8 on R8)
__global__ __launch_bounds__(1024, 4) void pow256_reduce1(const ushort_t* R64h, const ushort_t* R64l,
                                                          float* R256fp, ushort_t* R256h, ushort_t* R256l,
                                                          const ushort_t* R8h, const ushort_t* R8l,
                                                          const float* V1, float* V2) {
  __shared__ __attribute__((aligned(16))) char arena[49152];
  int blk = blockIdx.x;
  if (blk < 16)
    chain_body<0, 4>(arena, R64h, R64l, nullptr, nullptr, R256fp, R256h, R256l, blk);
  else
    chain_body<1, 8>(arena, R8h, R8l, nullptr, V1, V2, nullptr, nullptr, blk - 16);
}

// reduce2: 128 chains of CLEN=4 over V2[512] with R64 weights (8 blocks)
__global__ __launch_bounds__(1024, 4) void reduce2_k(const ushort_t* R64h, const ushort_t* R64l,
                                                     const float* V2, float* V3) {
  __shared__ __attribute__((aligned(16))) char arena[49152];
  chain_body<1, 4>(arena, R64h, R64l, nullptr, V2, V3, nullptr, nullptr, blockIdx.x);
}

// expand2: X2[512] from X3[128] + V2, CLEN=4, R64 (8 blocks)
__global__ __launch_bounds__(1024, 4) void expand2_k(const ushort_t* R64h, const ushort_t* R64l,
                                                     const float* X3, const float* V2, float* X2) {
  __shared__ __attribute__((aligned(16))) char arena[114688];
  chain_body<2, 4>(arena, R64h, R64l, X3, V2, X2, nullptr, nullptr, blockIdx.x);
}

__global__ __launch_bounds__(1024, 4) void expand1_k(const ushort_t* R8h, const ushort_t* R8l,
                                                     const float* X2, const float* V1, float* X1) {
  __shared__ __attribute__((aligned(16))) char arena[114688];
  chain_body<2, 8>(arena, R8h, R8l, X2, V1, X1, nullptr, nullptr, blockIdx.x);
}

__global__ __launch_bounds__(1024, 4) void expand0_k(const ushort_t* Rh, const ushort_t* Rl,
                                                     const float* X1, const float* V0, float* xout) {
  __shared__ __attribute__((aligned(16))) char arena[114688];
  chain_body<2, 8>(arena, Rh, Rl, X1, V0, xout, nullptr, nullptr, blockIdx.x);
}

// ---------------------------------------------------------------------------
// y = x @ C^T + u @ D^T. Register-tiled 4x4 (v5-verified). 256 blocks x 256
// thr. C/D stored TRANSPOSED in LDS (conflict-free); x from global (L2/L3).
__global__ __launch_bounds__(256) void y_kernel(const float* __restrict__ x, const float* __restrict__ u,
                                                const float* __restrict__ Cm, const float* __restrict__ Dm,
                                                float* __restrict__ y) {
  __shared__ float CsT[256][36];
  __shared__ float DsT[32][36];
  int tid = threadIdx.x;
  for (int k = tid; k < 8192; k += 256) CsT[k & 255][k >> 8] = Cm[k];
  for (int k = tid; k < 1024; k += 256) DsT[k & 31][k >> 5] = Dm[k];
  __syncthreads();
  int rt = tid >> 3, ct = tid & 7;
  int n0 = blockIdx.x * 128 + rt * 4;
  int o0 = ct * 4;
  float acc[4][4] = {{0.f}};
#pragma unroll 4
  for (int i = 0; i < 256; i += 4) {
    float4 cv0 = *(const float4*)&CsT[i + 0][o0];
    float4 cv1 = *(const float4*)&CsT[i + 1][o0];
    float4 cv2 = *(const float4*)&CsT[i + 2][o0];
    float4 cv3 = *(const float4*)&CsT[i + 3][o0];
#pragma unroll
    for (int r = 0; r < 4; r++) {
      float4 xv = *(const float4*)(x + (size_t)(n0 + r) * 256 + i);
      acc[r][0] += xv.x * cv0.x + xv.y * cv1.x + xv.z * cv2.x + xv.w * cv3.x;
      acc[r][1] += xv.x * cv0.y + xv.y * cv1.y + xv.z * cv2.y + xv.w * cv3.y;
      acc[r][2] += xv.x * cv0.z + xv.y * cv1.z + xv.z * cv2.z + xv.w * cv3.z;
      acc[r][3] += xv.x * cv0.w + xv.y * cv1.w + xv.z * cv2.w + xv.w * cv3.w;
    }
  }
#pragma unroll
  for (int i = 0; i < 32; i += 4) {
    float4 dv0 = *(const float4*)&DsT[i + 0][o0];
    float4 dv1 = *(const float4*)&DsT[i + 1][o0];
    float4 dv2 = *(const float4*)&DsT[i + 2][o0];
    float4 dv3 = *(const float4*)&DsT[i + 3][o0];
#pragma unroll
    for (int r = 0; r < 4; r++) {
      float4 uv = *(const float4*)(u + (size_t)(n0 + r) * 32 + i);
      acc[r][0] += uv.x * dv0.x + uv.y * dv1.x + uv.z * dv2.x + uv.w * dv3.x;
      acc[r][1] += uv.x * dv0.y + uv.y * dv1.y + uv.z * dv2.y + uv.w * dv3.y;
      acc[r][2] += uv.x * dv0.z + uv.y * dv1.z + uv.z * dv2.z + uv.w * dv3.z;
      acc[r][3] += uv.x * dv0.w + uv.y * dv1.w + uv.z * dv2.w + uv.w * dv3.w;
    }
  }
#pragma unroll
  for (int r = 0; r < 4; r++)
    *(float4*)(y + (size_t)(n0 + r) * 32 + o0) =
        make_float4(acc[r][0], acc[r][1], acc[r][2], acc[r][3]);
}

// ---------------------------------------------------------------------------
// AT = A^T (256x256)
__global__ __launch_bounds__(256) void transpose_at(const float* __restrict__ A, float* __restrict__ AT) {
  __shared__ float tile[64][65];
  int bx = blockIdx.x & 3, by = blockIdx.x >> 2;
  int r0 = by * 64, c0 = bx * 64;
  int t = threadIdx.x;
  int lr = t >> 4, lc = (t & 15) * 4;
  for (int rr = lr; rr < 64; rr += 16) {
    float4 v = *(const float4*)(A + (size_t)(r0 + rr) * 256 + c0 + lc);
    tile[rr][lc + 0] = v.x; tile[rr][lc + 1] = v.y; tile[rr][lc + 2] = v.z; tile[rr][lc + 3] = v.w;
  }
  __syncthreads();
  for (int rr = lr; rr < 64; rr += 16) {
    float4 v = make_float4(tile[lc + 0][rr], tile[lc + 1][rr], tile[lc + 2][rr], tile[lc + 3][rr]);
    *(float4*)(AT + (size_t)(c0 + rr) * 256 + r0 + lc) = v;
  }
}

// Unit responses through one Dopri5 step: cols 0..255 -> R fp32 + bf16 hi/lo
// split; cols 256..383 -> Hermite-folded tap matrices, bf16 hi/lo split,
// stored TRANSPOSED as Fh/Fl[n][k] (B-frag-ready for drive_body).
// 1024 threads = 4 j-groups x 256 rows; 4-way split-K with LDS reduce.
__global__ __launch_bounds__(1024) void unit_resp(const float* __restrict__ AT,
                                                  const float* __restrict__ Bm,
                                                  float* __restrict__ Rout,
                                                  ushort_t* __restrict__ Rh,
                                                  ushort_t* __restrict__ Rl,
                                                  ushort_t* __restrict__ Fh,
                                                  ushort_t* __restrict__ Fl) {
  int blk = blockIdx.x;
  int tid = threadIdx.x;
  int jg = tid >> 8;   // j-group 0..3, also the owned column index cc
  int i = tid & 255;   // output row
  int cc = jg;
  int col = blk * 4 + cc;

  __shared__ float xs4[256][4];
  __shared__ float4 part[4][256];

  const float AA[6][5] = {
      {0.f, 0.f, 0.f, 0.f, 0.f},
      {0.2f, 0.f, 0.f, 0.f, 0.f},
      {3.f / 40.f, 9.f / 40.f, 0.f, 0.f, 0.f},
      {44.f / 45.f, -56.f / 15.f, 32.f / 9.f, 0.f, 0.f},
      {19372.f / 6561.f, -25360.f / 2187.f, 64448.f / 6561.f, -212.f / 729.f, 0.f},
      {9017.f / 3168.f, -355.f / 33.f, 46732.f / 5247.f, 49.f / 176.f, -5103.f / 18656.f}};
  const float BB[6] = {35.f / 384.f, 0.f, 500.f / 1113.f, 125.f / 192.f, -2187.f / 6784.f, 11.f / 84.f};
  const float sv[6] = {0.f, 0.2f, 0.3f, 0.8f, 8.f / 9.f, 1.f};
  float Hm[6][4];
#pragma unroll
  for (int s = 0; s < 6; s++) {
    float ss = sv[s], s2 = ss * ss, s3 = s2 * ss;
    Hm[s][0] = 2.f * s3 - 3.f * s2 + 1.f;
    Hm[s][1] = s3 - 2.f * s2 + ss;
    Hm[s][2] = -2.f * s3 + 3.f * s2;
    Hm[s][3] = s3 - s2;
  }

  // owned-column metadata
  int isF, tt;
  float brow, xc;
  if (col < 256) {
    isF = 0; tt = 0; brow = 0.f;
    xc = (i == col) ? 1.f : 0.f;
  } else {
    isF = 1; xc = 0.f;
    int f = col - 256;
    tt = f >> 5;
    brow = Bm[i * 32 + (f & 31)];
  }
  float bh[6];
#pragma unroll
  for (int s = 0; s < 6; s++) {
    float hv = (tt == 0) ? Hm[s][0] : ((tt == 1) ? Hm[s][1] : ((tt == 2) ? Hm[s][2] : Hm[s][3]));
    bh[s] = isF ? hv * brow : 0.f;
  }

  float kreg[6];
#pragma unroll
  for (int s = 0; s < 6; s++) kreg[s] = 0.f;

  int j0 = jg * 64;
#pragma unroll 1
  for (int s = 0; s < 6; s++) {
    float xsv = xc;
#pragma unroll
    for (int j = 0; j < 5; j++)
      if (j < s) xsv += AA[s][j] * kreg[j];
    xs4[i][cc] = xsv;
    __syncthreads();
    float acx = 0.f, acy = 0.f, acz = 0.f, acw = 0.f;
#pragma unroll 8
    for (int jj = 0; jj < 64; jj++) {
      int j = j0 + jj;
      float a = AT[(size_t)j * 256 + i];
      float4 xv = *(const float4*)xs4[j];
      acx += a * xv.x;
      acy += a * xv.y;
      acz += a * xv.z;
      acw += a * xv.w;
    }
    part[jg][i] = make_float4(acx, acy, acz, acw);
    __syncthreads();
    float k = bh[s];
#pragma unroll
    for (int g = 0; g < 4; g++) {
      const float* p = (const float*)&part[g][i];
      k += p[cc];
    }
    kreg[s] = k;
  }

  float o = xc;
#pragma unroll
  for (int s = 0; s < 6; s++) o += BB[s] * kreg[s];
  if (!isF) {
    Rout[(size_t)i * 256 + col] = o;
    ushort_t h = bf16_hi(o);
    Rh[(size_t)i * 256 + col] = h;
    Rl[(size_t)i * 256 + col] = bf16_hi(o - bf16_f(h));
  } else {
    int f = col - 256;
    ushort_t h = bf16_hi(o);
    Fh[(size_t)i * 128 + f] = h;
    Fl[(size_t)i * 128 + f] = bf16_hi(o - bf16_f(h));
  }
}

// Top-level starts at stride 256: 128 blocks. X3[k] = x_{256k}.
// 4-term truncated recurrence on R^256 (exact k<=3; k>=4 drops
// ||R^1024||*X ~ 6e-5):
//   lo = max(0, k-3); vec = (k<=3 ? x0 : V3[k-4]);
//   for j=lo..k-1: vec = V3[j] + R256*vec;  X3[k] = vec.   (<=3 matvecs)
__global__ __launch_bounds__(256) void top_scan(const float* __restrict__ V3, const float* __restrict__ x0,
                                                const float* __restrict__ R256, float* __restrict__ X3) {
  int k = blockIdx.x, i = threadIdx.x;
  if (k == 0) { X3[i] = x0[i]; return; }
  __shared__ float buf[2][256];
  int lo = (k <= 3) ? 0 : (k - 3);
  const float* seed = (k <= 3) ? x0 : (V3 + (size_t)(k - 4) * 256);
  buf[0][i] = seed[i];
  __syncthreads();
  int cur = 0;
  for (int j = lo; j < k; j++) {
    float acc = V3[(size_t)j * 256 + i];
    const float* rr = R256 + (size_t)i * 256;
    const float* v = buf[cur];
    for (int jj = 0; jj < 256; jj += 4) {
      float4 rv = *(const float4*)(rr + jj);
      acc += rv.x * v[jj] + rv.y * v[jj + 1] + rv.z * v[jj + 2] + rv.w * v[jj + 3];
    }
    __syncthreads();
    buf[cur ^ 1][i] = acc;
    __syncthreads();
    cur ^= 1;
  }
  X3[(size_t)k * 256 + i] = buf[cur][i];
}

extern "C" void kernel_launch(void* const* d_in, const int* in_sizes, int n_in,
                              void* d_out, int out_size, void* d_ws, size_t ws_size,
                              hipStream_t stream) {
  const float* u  = (const float*)d_in[1];
  const float* x0 = (const float*)d_in[2];
  const float* A  = (const float*)d_in[3];
  const float* Bm = (const float*)d_in[4];
  const float* Cm = (const float*)d_in[5];
  const float* Dm = (const float*)d_in[6];
  float* xout = (float*)d_out;                       // [32768][256]
  float* yout = xout + (size_t)TPTS * 256;           // [32768][32]

  char* wsb = (char*)d_ws;
  size_t off = 0;
  auto alloc = [&](size_t bytes) -> void* {
    void* p = (void*)(wsb + off);
    off = (off + bytes + 255) & ~(size_t)255;
    return p;
  };
  float*    Rfp    = (float*)alloc(65536 * 4);
  ushort_t* Rh     = (ushort_t*)alloc(65536 * 2);
  ushort_t* Rl     = (ushort_t*)alloc(65536 * 2);
  float*    PowFp  = (float*)alloc(65536 * 4);       // scratch fp out for R^8/R^64
  ushort_t* R8h    = (ushort_t*)alloc(65536 * 2);
  ushort_t* R8l    = (ushort_t*)alloc(65536 * 2);
  ushort_t* R64h   = (ushort_t*)alloc(65536 * 2);
  ushort_t* R64l   = (ushort_t*)alloc(65536 * 2);
  float*    R256fp = (float*)alloc(65536 * 4);
  ushort_t* R256h  = (ushort_t*)alloc(65536 * 2);
  ushort_t* R256l  = (ushort_t*)alloc(65536 * 2);
  float*    ATm    = (float*)alloc(65536 * 4);
  ushort_t* Fh     = (ushort_t*)alloc(256 * 128 * 2);
  ushort_t* Fl     = (ushort_t*)alloc(256 * 128 * 2);
  float*    V0     = (float*)alloc((size_t)TPTS * 256 * 4);
  float*    V1     = (float*)alloc(4096 * 256 * 4);
  float*    V2     = (float*)alloc(512 * 256 * 4);
  float*    V3     = (float*)alloc(128 * 256 * 4);
  float*    X3     = (float*)alloc(128 * 256 * 4);
  float*    X2     = (float*)alloc(512 * 256 * 4);
  float*    X1     = (float*)alloc(4096 * 256 * 4);
  (void)ws_size; (void)in_sizes; (void)n_in; (void)out_size;

  // 1. A^T; unit responses -> R (fp32 + hi/lo) and Fh/Fl
  transpose_at<<<dim3(16), dim3(256), 0, stream>>>(A, ATm);
  unit_resp<<<dim3(96), dim3(1024), 0, stream>>>(ATm, Bm, Rfp, Rh, Rl, Fh, Fl);

  // 2. pow8 (16 blk) || MFMA drive GEMM (512 blk)
  pow8_gemm<<<dim3(528), dim3(1024), 0, stream>>>(Rh, Rl, PowFp, R8h, R8l, u, Fh, Fl, V0);

  // 3. pow64 (16) || reduce0 (256; 4096 chains of 8 over V0)
  pow64_reduce0<<<dim3(272), dim3(1024), 0, stream>>>(R8h, R8l, PowFp, R64h, R64l, Rh, Rl, V0, V1);

  // 4. pow256 = (R^64)^4 (16) || reduce1 (32; 512 chains of 8 over V1)
  pow256_reduce1<<<dim3(48), dim3(1024), 0, stream>>>(R64h, R64l, R256fp, R256h, R256l, R8h, R8l, V1, V2);

  // 5. reduce2 (8; 128 chains of 4 over V2), top starts (128), expand down
  reduce2_k<<<dim3(8), dim3(1024), 0, stream>>>(R64h, R64l, V2, V3);
  top_scan<<<dim3(128), dim3(256), 0, stream>>>(V3, x0, R256fp, X3);
  expand2_k<<<dim3(8), dim3(1024), 0, stream>>>(R64h, R64l, X3, V2, X2);
  expand1_k<<<dim3(32), dim3(1024), 0, stream>>>(R8h, R8l, X2, V1, X1);

  // 6. expand0, then y (separate launches — fused carried +64MB excess, r8/r9)
  expand0_k<<<dim3(256), dim3(1024), 0, stream>>>(Rh, Rl, X1, V0, xout);
  y_kernel<<<dim3(256), dim3(256), 0, stream>>>(xout, u, Cm, Dm, yout);
}